// Round 2
// baseline (2433.036 us; speedup 1.0000x reference)
//
#include <hip/hip_runtime.h>
#include <math.h>

// Problem constants
#define B_   32
#define L_   128
#define W_   16
#define CE_  64     // char embed
#define NF_  128    // num filters
#define WE_  256    // word embed
#define E_   384    // NF_ + WE_
#define H_   512
#define G4_  2048   // 4*H
#define O1_  512
#define NC_  17

// ---------------------------------------------------------------------------
// Kernel 0: transpose conv weights [F][C][K] -> [C][K][F] for coalesced reads
// ---------------------------------------------------------------------------
__global__ __launch_bounds__(256) void conv_transpose_k(
    const float* __restrict__ cw, float* __restrict__ cwT)
{
    int i = blockIdx.x * 256 + threadIdx.x;   // 128*64*3 = 24576 exact
    int f = i / 192;
    int rem = i - f * 192;
    int c = rem / 3;
    int k = rem - c * 3;
    cwT[(c * 3 + k) * NF_ + f] = cw[i];
}

// ---------------------------------------------------------------------------
// Kernel 1: char embed gather + conv1d(k=3,pad=1) + relu + maxpool + word
// embed concat -> x [B*L, 384].  One block per (b,l), 64 threads,
// 2 filters/thread.
// ---------------------------------------------------------------------------
__global__ __launch_bounds__(64) void embed_cnn(
    const int* __restrict__ word_ids, const int* __restrict__ char_ids,
    const float* __restrict__ char_emb, const float* __restrict__ word_emb,
    const float* __restrict__ cwT, const float* __restrict__ conv_b,
    float* __restrict__ x)
{
    __shared__ float ce[CE_][20];   // [c][w+1]; slots 0..17 used (0,17 = pad)
    __shared__ int ids[W_];
    int bl = blockIdx.x;            // 0..4095, bl = b*L + l
    int tid = threadIdx.x;          // 0..63

    if (tid < W_) ids[tid] = char_ids[bl * W_ + tid];
    ce[tid][0] = 0.f;
    ce[tid][17] = 0.f;
    __syncthreads();

    for (int i = tid; i < W_ * CE_; i += 64) {
        int w = i >> 6, c = i & 63;
        ce[c][w + 1] = char_emb[ids[w] * CE_ + c];
    }
    __syncthreads();

    int f0 = tid, f1 = tid + 64;
    float acc0[W_], acc1[W_];
#pragma unroll
    for (int w = 0; w < W_; w++) { acc0[w] = 0.f; acc1[w] = 0.f; }

    for (int c = 0; c < CE_; c++) {
        float win[18];
        float4 v0 = *(const float4*)&ce[c][0];
        float4 v1 = *(const float4*)&ce[c][4];
        float4 v2 = *(const float4*)&ce[c][8];
        float4 v3 = *(const float4*)&ce[c][12];
        win[0]=v0.x; win[1]=v0.y; win[2]=v0.z; win[3]=v0.w;
        win[4]=v1.x; win[5]=v1.y; win[6]=v1.z; win[7]=v1.w;
        win[8]=v2.x; win[9]=v2.y; win[10]=v2.z; win[11]=v2.w;
        win[12]=v3.x; win[13]=v3.y; win[14]=v3.z; win[15]=v3.w;
        win[16] = ce[c][16];
        win[17] = ce[c][17];
        const float* wp = cwT + c * 3 * NF_;
        float k00 = wp[f0], k01 = wp[NF_ + f0], k02 = wp[2 * NF_ + f0];
        float k10 = wp[f1], k11 = wp[NF_ + f1], k12 = wp[2 * NF_ + f1];
#pragma unroll
        for (int w = 0; w < W_; w++) {
            acc0[w] += win[w] * k00 + win[w + 1] * k01 + win[w + 2] * k02;
            acc1[w] += win[w] * k10 + win[w + 1] * k11 + win[w + 2] * k12;
        }
    }
    float m0 = acc0[0], m1 = acc1[0];
#pragma unroll
    for (int w = 1; w < W_; w++) { m0 = fmaxf(m0, acc0[w]); m1 = fmaxf(m1, acc1[w]); }
    m0 = fmaxf(0.f, m0 + conv_b[f0]);
    m1 = fmaxf(0.f, m1 + conv_b[f1]);
    x[bl * E_ + f0] = m0;
    x[bl * E_ + f1] = m1;

    // word embedding: 256 floats, 1 float4 per thread
    int wid = word_ids[bl];
    float4 wv = *(const float4*)&word_emb[wid * WE_ + tid * 4];
    *(float4*)&x[bl * E_ + NF_ + tid * 4] = wv;
}

// ---------------------------------------------------------------------------
// Kernel 2: generic tiled fp32 GEMM  C = A[M,K] @ W[N,K]^T + bias, with
// optional ELU and output-row remap (mode 0: none, 1: fwd time-major,
// 2: bwd reversed time-major).  64x64 tile, BK=16, 4x4 per thread.
// ---------------------------------------------------------------------------
__global__ __launch_bounds__(256) void gemm_bias_act(
    const float* __restrict__ A, const float* __restrict__ Wt,
    const float* __restrict__ bias, float* __restrict__ C,
    int M, int N, int K, int mode, int act)
{
    __shared__ float As[16][68];
    __shared__ float Bs[16][68];
    int tid = threadIdx.x;
    int bm = blockIdx.x * 64;
    int bn = blockIdx.y * 64;
    int tx = tid & 15, ty = tid >> 4;
    int r = tid >> 2, kq = (tid & 3) << 2;
    float acc[4][4] = {};

    for (int kt = 0; kt < K; kt += 16) {
        float4 av = *(const float4*)&A[(bm + r) * K + kt + kq];
        As[kq + 0][r] = av.x; As[kq + 1][r] = av.y;
        As[kq + 2][r] = av.z; As[kq + 3][r] = av.w;
        int n = bn + r;
        float4 wv = make_float4(0.f, 0.f, 0.f, 0.f);
        if (n < N) wv = *(const float4*)&Wt[n * K + kt + kq];
        Bs[kq + 0][r] = wv.x; Bs[kq + 1][r] = wv.y;
        Bs[kq + 2][r] = wv.z; Bs[kq + 3][r] = wv.w;
        __syncthreads();
#pragma unroll
        for (int k = 0; k < 16; k++) {
            float4 a = *(const float4*)&As[k][ty << 2];
            float4 b = *(const float4*)&Bs[k][tx << 2];
            acc[0][0] += a.x * b.x; acc[0][1] += a.x * b.y;
            acc[0][2] += a.x * b.z; acc[0][3] += a.x * b.w;
            acc[1][0] += a.y * b.x; acc[1][1] += a.y * b.y;
            acc[1][2] += a.y * b.z; acc[1][3] += a.y * b.w;
            acc[2][0] += a.z * b.x; acc[2][1] += a.z * b.y;
            acc[2][2] += a.z * b.z; acc[2][3] += a.z * b.w;
            acc[3][0] += a.w * b.x; acc[3][1] += a.w * b.y;
            acc[3][2] += a.w * b.z; acc[3][3] += a.w * b.w;
        }
        __syncthreads();
    }

#pragma unroll
    for (int ii = 0; ii < 4; ii++) {
        int m = bm + (ty << 2) + ii;
        int orow;
        if (mode == 0) orow = m;
        else {
            int bb = m >> 7, l = m & 127;
            int ll = (mode == 1) ? l : (127 - l);
            orow = ll * B_ + bb;
        }
#pragma unroll
        for (int jj = 0; jj < 4; jj++) {
            int n = bn + (tx << 2) + jj;
            if (n < N) {
                float v = acc[ii][jj] + bias[n];
                if (act) v = v > 0.f ? v : expm1f(v);
                C[orow * N + n] = v;
            }
        }
    }
}

// ---------------------------------------------------------------------------
// Kernel 3: one BLSTM time step (both directions).
// grid = 256 blocks: dir = bx>>7, 4 hidden units per block (16 gate rows).
// Thread (rr,b) computes gate rows rr and rr+8 over K=512, then 128 threads
// apply the cell update and scatter h into hcat.
// h layout: [dir][H][B] (batch fastest).
// ---------------------------------------------------------------------------
__global__ __launch_bounds__(256) void lstm_step(
    int t,
    const float* __restrict__ gxf, const float* __restrict__ gxb,
    const float* __restrict__ whh_f, const float* __restrict__ whh_b,
    const float* __restrict__ h_prev, float* __restrict__ h_next,
    float* __restrict__ cst, float* __restrict__ hcat)
{
    int bx = blockIdx.x;
    int dir = bx >> 7;
    int U0 = (bx & 127) * 4;
    int tid = threadIdx.x;
    int b = tid & 31, rr = tid >> 5;      // rr 0..7

    const float* gx  = dir ? gxb : gxf;
    const float* whh = dir ? whh_b : whh_f;
    const float* hp  = h_prev + dir * H_ * B_;

    int r0 = rr, r1 = rr + 8;             // local rows (gate*4 + unit)
    int R0 = (r0 >> 2) * H_ + U0 + (r0 & 3);
    int R1 = (r1 >> 2) * H_ + U0 + (r1 & 3);
    float acc0 = gx[(t * B_ + b) * G4_ + R0];
    float acc1 = gx[(t * B_ + b) * G4_ + R1];
    const float* w0 = whh + R0 * H_;
    const float* w1 = whh + R1 * H_;

    for (int k = 0; k < H_; k += 4) {
        float4 wv0 = *(const float4*)&w0[k];
        float4 wv1 = *(const float4*)&w1[k];
        float h0 = hp[(k + 0) * B_ + b];
        float h1 = hp[(k + 1) * B_ + b];
        float h2 = hp[(k + 2) * B_ + b];
        float h3 = hp[(k + 3) * B_ + b];
        acc0 += wv0.x * h0 + wv0.y * h1 + wv0.z * h2 + wv0.w * h3;
        acc1 += wv1.x * h0 + wv1.y * h1 + wv1.z * h2 + wv1.w * h3;
    }

    __shared__ float gl[16][32];
    gl[r0][b] = acc0;
    gl[r1][b] = acc1;
    __syncthreads();

    if (tid < 128) {
        int u = tid >> 5;                 // 0..3, b = tid&31
        float gi = gl[u][b];
        float gf = gl[4 + u][b];
        float gg = gl[8 + u][b];
        float go = gl[12 + u][b];
        int j = U0 + u;
        float* cp = cst + (dir * H_ + j) * B_ + b;
        float c_old = *cp;
        float i_ = 1.f / (1.f + expf(-gi));
        float f_ = 1.f / (1.f + expf(-gf));
        float o_ = 1.f / (1.f + expf(-go));
        float g_ = tanhf(gg);
        float c_new = f_ * c_old + i_ * g_;
        float h_new = o_ * tanhf(c_new);
        *cp = c_new;
        h_next[(dir * H_ + j) * B_ + b] = h_new;
        int l = dir ? (L_ - 1 - t) : t;
        hcat[(b * L_ + l) * (2 * H_) + dir * H_ + j] = h_new;
    }
}

// ---------------------------------------------------------------------------
// Launch
// ---------------------------------------------------------------------------
extern "C" void kernel_launch(void* const* d_in, const int* in_sizes, int n_in,
                              void* d_out, int out_size, void* d_ws, size_t ws_size,
                              hipStream_t stream)
{
    const int*   word_ids = (const int*)d_in[0];
    const int*   char_ids = (const int*)d_in[1];
    // d_in[2] = mask (unused by reference)
    const float* char_emb = (const float*)d_in[3];
    const float* word_emb = (const float*)d_in[4];
    const float* conv_w   = (const float*)d_in[5];
    const float* conv_b   = (const float*)d_in[6];
    const float* w_ih_f   = (const float*)d_in[7];
    const float* w_hh_f   = (const float*)d_in[8];
    const float* b_f      = (const float*)d_in[9];
    const float* w_ih_b   = (const float*)d_in[10];
    const float* w_hh_b   = (const float*)d_in[11];
    const float* b_b      = (const float*)d_in[12];
    const float* w1       = (const float*)d_in[13];
    const float* b1       = (const float*)d_in[14];
    const float* w2       = (const float*)d_in[15];
    const float* b2       = (const float*)d_in[16];
    float* out = (float*)d_out;
    float* ws  = (float*)d_ws;

    // workspace layout (floats); total 24,764,416 floats = ~99 MB
    float* x    = ws + 0;          // [4096][384]
    float* gxf  = ws + 1572864;    // [128][32][2048]
    float* gxb  = ws + 9961472;    // [128][32][2048]
    float* hA   = ws + 18350080;   // [2][512][32]
    float* hB   = ws + 18382848;   // [2][512][32]
    float* cst  = ws + 18415616;   // [2][512][32]
    float* hcat = ws + 18448384;   // [4096][1024]
    float* z    = ws + 22642688;   // [4096][512]
    float* cwT  = ws + 24739840;   // [64][3][128]

    hipMemsetAsync(hA,  0, 2 * H_ * B_ * sizeof(float), stream);
    hipMemsetAsync(cst, 0, 2 * H_ * B_ * sizeof(float), stream);

    conv_transpose_k<<<96, 256, 0, stream>>>(conv_w, cwT);
    embed_cnn<<<4096, 64, 0, stream>>>(word_ids, char_ids, char_emb, word_emb,
                                       cwT, conv_b, x);

    dim3 g1(64, 32);
    gemm_bias_act<<<g1, 256, 0, stream>>>(x, w_ih_f, b_f, gxf, 4096, G4_, E_, 1, 0);
    gemm_bias_act<<<g1, 256, 0, stream>>>(x, w_ih_b, b_b, gxb, 4096, G4_, E_, 2, 0);

    float* hp = hA; float* hn = hB;
    for (int t = 0; t < L_; t++) {
        lstm_step<<<256, 256, 0, stream>>>(t, gxf, gxb, w_hh_f, w_hh_b,
                                           hp, hn, cst, hcat);
        float* tmp = hp; hp = hn; hn = tmp;
    }

    dim3 g2(64, 8);
    gemm_bias_act<<<g2, 256, 0, stream>>>(hcat, w1, b1, z, 4096, O1_, 2 * H_, 0, 1);
    dim3 g3(64, 1);
    gemm_bias_act<<<g3, 256, 0, stream>>>(z, w2, b2, out, 4096, NC_, O1_, 0, 0);
}